// Round 7
// baseline (2858.352 us; speedup 1.0000x reference)
//
#include <hip/hip_runtime.h>
#include <cstddef>

// ---------------------------------------------------------------------------
// VQ-VAE forward. Round 7: MFMA (fp16 hi/lo split) now also covers
// dec1/dec2 ConvTranspose (4-parity-class gather) and enc1's stride-2 conv.
// fp32 kernels remain only for enc0's 3-channel conv, 1x1 convs, quantize.
// ---------------------------------------------------------------------------

typedef float v4f __attribute__((ext_vector_type(4)));
typedef _Float16 f16x8 __attribute__((ext_vector_type(8)));

__device__ __forceinline__ void fma4(v4f& a, float p, const v4f& w) {
    a.x = fmaf(p, w.x, a.x); a.y = fmaf(p, w.y, a.y);
    a.z = fmaf(p, w.z, a.z); a.w = fmaf(p, w.w, a.w);
}

// Repack conv weights to fp32 [ci][9][cout] (fp32 kernels).
__global__ void repack_k(const float* __restrict__ src, float* __restrict__ dst,
                         int cout, int coutR, int cin, int flip, int deconv)
{
    int t = blockIdx.x * 256 + threadIdx.x;
    int tot = cin * 9 * cout;
    if (t >= tot) return;
    int co = t % cout; int k = (t / cout) % 9; int ci = t / (9 * cout);
    float v = 0.f;
    if (co < coutR) {
        int ks = flip ? 8 - k : k;
        v = deconv ? src[((size_t)ci * coutR + co) * 9 + ks]
                   : src[((size_t)co * cin + ci) * 9 + ks];
    }
    dst[t] = v;
}

// Prepack conv weights to fp16 hi/lo MFMA B-fragment order (9 taps):
// 16B-block = ((tap*C32 + c32)*NGtot + ng); element j: co = ng*16 + (lane&15),
// ci = c32*32 + ((lane>>4)&3)*8 + j.  deconv=1: src (cin,cout,3,3), flipped.
__global__ void repackB16_k(const float* __restrict__ src, _Float16* __restrict__ bh,
                            _Float16* __restrict__ bl, int COUT, int CIN, int deconv)
{
    int t = blockIdx.x * 256 + threadIdx.x;
    int tot = 9 * CIN * COUT;
    if (t >= tot) return;
    int NGtot = COUT >> 4, C32 = CIN >> 5;
    int j = t & 7;
    int lane = (t >> 3) & 63;
    int blk = t >> 9;
    int ng = blk % NGtot; blk /= NGtot;
    int c32 = blk % C32;
    int tap = blk / C32;
    int co = ng * 16 + (lane & 15);
    int ci = c32 * 32 + ((lane >> 4) & 3) * 8 + j;
    float v = deconv ? src[((size_t)ci * COUT + co) * 9 + (8 - tap)]
                     : src[((size_t)co * CIN + ci) * 9 + tap];
    _Float16 h = (_Float16)v;
    _Float16 l = (_Float16)(v - (float)h);
    bh[t] = h; bl[t] = l;
}

// Prepack ConvTranspose-s2 weights to class/tap B-fragment order.
// 16 slots (cls*4 + t); cls=(a<<1)|b; t -> di=t/(b+1), dj=t%(b+1);
// ky = a? (di?0:2) : 1; kx = b? (dj?0:2) : 1. src (CIN, COUTR, 3, 3).
__global__ void repackBT_k(const float* __restrict__ src, _Float16* __restrict__ bh,
                           _Float16* __restrict__ bl, int COUTR, int NG, int CIN)
{
    int C32 = CIN >> 5;
    int t = blockIdx.x * 256 + threadIdx.x;
    int tot = 16 * C32 * NG * 512;
    if (t >= tot) return;
    int j = t & 7;
    int lane = (t >> 3) & 63;
    int blk = t >> 9;
    int ng = blk % NG; blk /= NG;
    int c32 = blk % C32;
    int slot = blk / C32;
    int cls = slot >> 2, tt = slot & 3;
    int a = cls >> 1, b = cls & 1;
    int co = ng * 16 + (lane & 15);
    int ci = c32 * 32 + ((lane >> 4) & 3) * 8 + j;
    float v = 0.f;
    if (tt < (a + 1) * (b + 1) && co < COUTR) {
        int di = tt / (b + 1), dj = tt % (b + 1);
        int ky = a ? (di ? 0 : 2) : 1;
        int kx = b ? (dj ? 0 : 2) : 1;
        v = src[(((size_t)ci * COUTR + co) * 3 + ky) * 3 + kx];
    }
    _Float16 h = (_Float16)v;
    _Float16 l = (_Float16)(v - (float)h);
    bh[t] = h; bl[t] = l;
}

// ================= MFMA 3x3 conv s1 p1 (fp16 hi/lo split) ===================
template<int CIN, bool RELU, bool ADDSELF>
__launch_bounds__(256, 3)
__global__ void mconv3s1_k(const float* __restrict__ in,
                           const _Float16* __restrict__ Bh, const _Float16* __restrict__ Bl,
                           const float* __restrict__ bias, float* __restrict__ out,
                           const float* __restrict__ addend,
                           int COUT, int H, int W)
{
    constexpr int C32 = CIN / 32;
    __shared__ __align__(16) unsigned char smBuf[53376];
    _Float16* AH = (_Float16*)smBuf;        // [10][18][40]
    _Float16* AL = AH + 7200;
    _Float16* BW = AL + 7200;               // [tapL3][ng4][hl2][512]
    float* smO = (float*)smBuf;             // [64][129] epilogue overlay

    const int tid = threadIdx.x;
    const int lane = tid & 63, yb = tid >> 6;
    const int n16 = lane & 15, q = lane >> 4;

    int b = blockIdx.x;
    const int chunks = COUT >> 6;
    const int coch = b % chunks; b /= chunks;
    const int tX = W >> 4; const int tx = b % tX; b /= tX;
    const int tY = H >> 3; const int ty = b % tY; const int n = b / tY;
    const int x0 = tx * 16, y0 = ty * 8;
    const int NGtot = COUT >> 4;
    const int ngbase = coch * 4, cobase = coch * 64;

    v4f acc[2][4];
#pragma unroll
    for (int ng = 0; ng < 4; ++ng) {
        float bb = bias[cobase + ng * 16 + n16];
        v4f bv = {bb, bb, bb, bb};
        acc[0][ng] = bv; acc[1][ng] = bv;
    }

    for (int c32 = 0; c32 < C32; ++c32) {
        __syncthreads();
        for (int u = tid; u < 5760; u += 256) {
            int ci = u / 180, rem = u - ci * 180;
            int yy = rem / 18, xx = rem - yy * 18;
            int gy = y0 - 1 + yy, gx = x0 - 1 + xx;
            float v = 0.f;
            if (gy >= 0 && gy < H && gx >= 0 && gx < W)
                v = in[(((size_t)n * CIN + c32 * 32 + ci) * H + gy) * W + gx];
            _Float16 h = (_Float16)v;
            _Float16 l = (_Float16)(v - (float)h);
            int a = (yy * 18 + xx) * 40 + ci;
            AH[a] = h; AL[a] = l;
        }
        for (int ky = 0; ky < 3; ++ky) {
            __syncthreads();
            for (int u = tid; u < 1536; u += 256) {
                int lu = u & 63;
                int rest = u >> 6;
                int hl = rest & 1; rest >>= 1;
                int ng = rest & 3;
                int tapL = rest >> 2;
                const uint4* srcp = (const uint4*)(hl ? Bl : Bh);
                size_t sidx = (((size_t)(ky * 3 + tapL) * C32 + c32) * NGtot + ngbase + ng) * 64 + lu;
                ((uint4*)BW)[u] = srcp[sidx];
            }
            __syncthreads();
#pragma unroll
            for (int kx = 0; kx < 3; ++kx) {
                f16x8 aH[2], aL[2];
#pragma unroll
                for (int mg = 0; mg < 2; ++mg) {
                    int aoff = ((2 * yb + mg + ky) * 18 + n16 + kx) * 40 + q * 8;
                    aH[mg] = *(const f16x8*)&AH[aoff];
                    aL[mg] = *(const f16x8*)&AL[aoff];
                }
#pragma unroll
                for (int ng = 0; ng < 4; ++ng) {
                    int boff = ((kx * 4 + ng) * 2) * 512 + lane * 8;
                    f16x8 bH = *(const f16x8*)&BW[boff];
                    f16x8 bL = *(const f16x8*)&BW[boff + 512];
#pragma unroll
                    for (int mg = 0; mg < 2; ++mg) {
                        acc[mg][ng] = __builtin_amdgcn_mfma_f32_16x16x32_f16(aH[mg], bH, acc[mg][ng], 0, 0, 0);
                        acc[mg][ng] = __builtin_amdgcn_mfma_f32_16x16x32_f16(aL[mg], bH, acc[mg][ng], 0, 0, 0);
                        acc[mg][ng] = __builtin_amdgcn_mfma_f32_16x16x32_f16(aH[mg], bL, acc[mg][ng], 0, 0, 0);
                    }
                }
            }
        }
    }

    __syncthreads();
#pragma unroll
    for (int mg = 0; mg < 2; ++mg)
#pragma unroll
        for (int ng = 0; ng < 4; ++ng) {
            int p = (2 * yb + mg) * 16 + q * 4;
            int co = ng * 16 + n16;
#pragma unroll
            for (int r = 0; r < 4; ++r)
                smO[co * 129 + p + r] = acc[mg][ng][r];
        }
    __syncthreads();
    const size_t plane = (size_t)H * W;
    float* ob = out + ((size_t)n * COUT + cobase) * plane;
    const float* ab = ADDSELF ? addend + ((size_t)n * COUT + cobase) * plane : nullptr;
#pragma unroll
    for (int k = 0; k < 32; ++k) {
        int e = tid + 256 * k;
        int co = e >> 7, p = e & 127;
        int py = p >> 4, px = p & 15;
        size_t g = (size_t)co * plane + (size_t)(y0 + py) * W + x0 + px;
        float v = smO[co * 129 + p];
        if (ADDSELF) v += ab[g];
        if (RELU) v = fmaxf(v, 0.f);
        ob[g] = v;
    }
}

// ============= MFMA 3x3 conv s2 p1 — 8x8 out tile, 32 co/block ==============
template<int CIN, bool RELU>
__launch_bounds__(256, 2)
__global__ void mconv3s2_k(const float* __restrict__ in,
                           const _Float16* __restrict__ Bh, const _Float16* __restrict__ Bl,
                           const float* __restrict__ bias, float* __restrict__ out,
                           int COUT, int Hin, int Win)
{
    constexpr int C32 = CIN / 32;
    __shared__ __align__(16) unsigned char smBuf[58528];
    _Float16* AH = (_Float16*)smBuf;        // [17*17][40]
    _Float16* AL = AH + 11560;
    _Float16* BW = AL + 11560;              // [kx3][ng2][hl2][512]
    float* smO = (float*)smBuf;             // [32][68] overlay

    const int tid = threadIdx.x;
    const int lane = tid & 63, yb = tid >> 6;
    const int n16 = lane & 15, q = lane >> 4;

    int b = blockIdx.x;
    const int chunks = COUT >> 5;           // 32 co per block
    const int coch = b % chunks; b /= chunks;
    const int Hout = Hin >> 1, Wout = Win >> 1;
    const int tX = Wout >> 3; const int tx = b % tX; b /= tX;
    const int tY = Hout >> 3; const int ty = b % tY; const int n = b / tY;
    const int x0 = tx * 8, y0 = ty * 8;
    const int NGtot = COUT >> 4;
    const int ngbase = coch * 2, cobase = coch * 32;

    v4f acc[2];
#pragma unroll
    for (int ng = 0; ng < 2; ++ng) {
        float bb = bias[cobase + ng * 16 + n16];
        v4f bv = {bb, bb, bb, bb};
        acc[ng] = bv;
    }

    for (int c32 = 0; c32 < C32; ++c32) {
        for (int ky = 0; ky < 3; ++ky) {
            __syncthreads();
            if (ky == 0) {
                for (int u = tid; u < 9248; u += 256) {
                    int ci = u / 289, rem = u - ci * 289;
                    int yy = rem / 17, xx = rem - yy * 17;
                    int gy = 2 * y0 - 1 + yy, gx = 2 * x0 - 1 + xx;
                    float v = 0.f;
                    if (gy >= 0 && gy < Hin && gx >= 0 && gx < Win)
                        v = in[(((size_t)n * CIN + c32 * 32 + ci) * Hin + gy) * Win + gx];
                    _Float16 h = (_Float16)v;
                    _Float16 l = (_Float16)(v - (float)h);
                    int a = (yy * 17 + xx) * 40 + ci;
                    AH[a] = h; AL[a] = l;
                }
            }
            for (int u = tid; u < 768; u += 256) {
                int lu = u & 63;
                int rest = u >> 6;
                int hl = rest & 1; rest >>= 1;
                int ng = rest & 1;
                int kxl = rest >> 1;
                const uint4* srcp = (const uint4*)(hl ? Bl : Bh);
                size_t sidx = (((size_t)(ky * 3 + kxl) * C32 + c32) * NGtot + ngbase + ng) * 64 + lu;
                ((uint4*)BW)[u] = srcp[sidx];
            }
            __syncthreads();
#pragma unroll
            for (int kx = 0; kx < 3; ++kx) {
                const int rowL = 2 * yb + (n16 >> 3), colL = n16 & 7;
                int aoff = ((2 * rowL + ky) * 17 + 2 * colL + kx) * 40 + q * 8;
                f16x8 aH = *(const f16x8*)&AH[aoff];
                f16x8 aL = *(const f16x8*)&AL[aoff];
#pragma unroll
                for (int ng = 0; ng < 2; ++ng) {
                    int boff = ((kx * 2 + ng) * 2) * 512 + lane * 8;
                    f16x8 bH = *(const f16x8*)&BW[boff];
                    f16x8 bL = *(const f16x8*)&BW[boff + 512];
                    acc[ng] = __builtin_amdgcn_mfma_f32_16x16x32_f16(aH, bH, acc[ng], 0, 0, 0);
                    acc[ng] = __builtin_amdgcn_mfma_f32_16x16x32_f16(aL, bH, acc[ng], 0, 0, 0);
                    acc[ng] = __builtin_amdgcn_mfma_f32_16x16x32_f16(aH, bL, acc[ng], 0, 0, 0);
                }
            }
        }
    }

    __syncthreads();
#pragma unroll
    for (int ng = 0; ng < 2; ++ng) {
        int coL = ng * 16 + n16;
#pragma unroll
        for (int r = 0; r < 4; ++r)
            smO[coL * 68 + 16 * yb + q * 4 + r] = acc[ng][r];
    }
    __syncthreads();
    const size_t plane = (size_t)Hout * Wout;
    float* ob = out + ((size_t)n * COUT + cobase) * plane;
#pragma unroll
    for (int k = 0; k < 8; ++k) {
        int e = tid + 256 * k;
        int coL = e >> 6, p = e & 63;
        int py = p >> 3, px = p & 7;
        float v = smO[coL * 68 + p];
        if (RELU) v = fmaxf(v, 0.f);
        ob[(size_t)coL * plane + (size_t)(y0 + py) * Wout + x0 + px] = v;
    }
}

// ====== MFMA ConvTranspose k3 s2 p1 op1 — 4 parity classes, gather form =====
// Block: input tile 8x16 -> output 16x32, NG*16 channels. 5 passes (<=2 taps).
template<int CIN, int NG, bool RELU>
__launch_bounds__(256, 3)
__global__ void mdeconv2_k(const float* __restrict__ in,
                           const _Float16* __restrict__ Bh, const _Float16* __restrict__ Bl,
                           const float* __restrict__ bias, float* __restrict__ out,
                           int COUTR, int H, int W)
{
    constexpr int C32 = CIN / 32;
    constexpr int AB = 24480;                       // 2*6120 halves * 2B
    constexpr int BB = NG * 4096;                   // 2 taps * NG * 2 * 512 * 2B
    constexpr int OB = NG * 16 * 132 * 4;
    constexpr int SMB = (AB + BB > OB) ? (AB + BB) : OB;
    __shared__ __align__(16) unsigned char smBuf[SMB];
    _Float16* AH = (_Float16*)smBuf;                // [9*17][40]
    _Float16* AL = AH + 6120;
    _Float16* BW = AL + 6120;                       // [t2][NG][hl2][512]
    float* smO = (float*)smBuf;                     // [NG*16][132]

    const int tid = threadIdx.x;
    const int lane = tid & 63, yb = tid >> 6;
    const int n16 = lane & 15, q = lane >> 4;

    int b = blockIdx.x;
    const int tX = W >> 4; const int tx = b % tX; b /= tX;
    const int tY = H >> 3; const int ty = b % tY; const int n = b / tY;
    const int ix0 = tx * 16, iy0 = ty * 8;

    const int clsA[5] = {0, 1, 2, 3, 3};
    const int t0A[5]  = {0, 0, 0, 0, 2};
    const int ntA[5]  = {1, 2, 2, 2, 2};

    v4f acc[2][NG];

    for (int p = 0; p < 5; ++p) {
        const int cl = clsA[p], t0 = t0A[p], nt = ntA[p];
        const int a = cl >> 1, b2 = cl & 1;
        if (t0 == 0) {
#pragma unroll
            for (int ng = 0; ng < NG; ++ng) {
                int co = ng * 16 + n16;
                float bb = (co < COUTR) ? bias[co] : 0.f;
                v4f bv = {bb, bb, bb, bb};
                acc[0][ng] = bv; acc[1][ng] = bv;
            }
        }
        for (int c32 = 0; c32 < C32; ++c32) {
            __syncthreads();
            for (int u = tid; u < 4896; u += 256) {
                int ci = u / 153, rem = u - ci * 153;
                int yy = rem / 17, xx = rem - yy * 17;
                int gy = iy0 + yy, gx = ix0 + xx;
                float v = 0.f;
                if (gy < H && gx < W)
                    v = in[(((size_t)n * CIN + c32 * 32 + ci) * H + gy) * W + gx];
                _Float16 h = (_Float16)v;
                _Float16 l = (_Float16)(v - (float)h);
                int aoff = (yy * 17 + xx) * 40 + ci;
                AH[aoff] = h; AL[aoff] = l;
            }
            for (int u = tid; u < nt * NG * 2 * 64; u += 256) {
                int lu = u & 63;
                int rest = u >> 6;
                int hl = rest & 1; rest >>= 1;
                int ng = rest % NG;
                int tl = rest / NG;
                int slot = cl * 4 + t0 + tl;
                const uint4* srcp = (const uint4*)(hl ? Bl : Bh);
                size_t sidx = (((size_t)slot * C32 + c32) * NG + ng) * 64 + lu;
                ((uint4*)BW)[u] = srcp[sidx];
            }
            __syncthreads();
#pragma unroll 1
            for (int tl = 0; tl < nt; ++tl) {
                int t = t0 + tl;
                int di = t / (b2 + 1), dj = t % (b2 + 1);
                f16x8 aH[2], aL[2];
#pragma unroll
                for (int mg = 0; mg < 2; ++mg) {
                    int aoff = ((2 * yb + mg + di) * 17 + n16 + dj) * 40 + q * 8;
                    aH[mg] = *(const f16x8*)&AH[aoff];
                    aL[mg] = *(const f16x8*)&AL[aoff];
                }
#pragma unroll
                for (int ng = 0; ng < NG; ++ng) {
                    int boff = ((tl * NG + ng) * 2) * 512 + lane * 8;
                    f16x8 bH = *(const f16x8*)&BW[boff];
                    f16x8 bL = *(const f16x8*)&BW[boff + 512];
#pragma unroll
                    for (int mg = 0; mg < 2; ++mg) {
                        acc[mg][ng] = __builtin_amdgcn_mfma_f32_16x16x32_f16(aH[mg], bH, acc[mg][ng], 0, 0, 0);
                        acc[mg][ng] = __builtin_amdgcn_mfma_f32_16x16x32_f16(aL[mg], bH, acc[mg][ng], 0, 0, 0);
                        acc[mg][ng] = __builtin_amdgcn_mfma_f32_16x16x32_f16(aH[mg], bL, acc[mg][ng], 0, 0, 0);
                    }
                }
            }
        }
        if (t0 + nt == (a + 1) * (b2 + 1)) {
            // epilogue for this class
            __syncthreads();
#pragma unroll
            for (int mg = 0; mg < 2; ++mg)
#pragma unroll
                for (int ng = 0; ng < NG; ++ng) {
                    int co = ng * 16 + n16;
                    int row = 2 * yb + mg;
#pragma unroll
                    for (int r = 0; r < 4; ++r)
                        smO[co * 132 + row * 16 + q * 4 + r] = acc[mg][ng][r];
                }
            __syncthreads();
#pragma unroll
            for (int k = 0; k < NG * 8; ++k) {
                int e = tid + 256 * k;
                int co = e >> 7, pp = e & 127;
                if (co < COUTR) {
                    int rI = pp >> 4, cI = pp & 15;
                    int oy = 2 * (iy0 + rI) + a;
                    int ox = 2 * (ix0 + cI) + b2;
                    float v = smO[co * 132 + pp];
                    if (RELU) v = fmaxf(v, 0.f);
                    out[(((size_t)n * COUTR + co) * (2 * H) + oy) * (2 * W) + ox] = v;
                }
            }
        }
    }
}

// ===================== fp32 3x3 conv s2 (enc0, CIN=3) =======================
template<int CIN, int CB, bool RELU>
__launch_bounds__(256, 4)
__global__ void conv3s2_k(const float* __restrict__ in, const float* __restrict__ wp,
                          const float* __restrict__ bias, float* __restrict__ out,
                          int COUT, int Hin, int Win)
{
    constexpr int COC = 32;
    __shared__ float smIn[CB * 2178];           // 33 x 66
    __shared__ float smW[CB * 9 * COC];
    const int Hout = Hin >> 1, Wout = Win >> 1;
    const int tid = threadIdx.x;
    int b = blockIdx.x;
    const int chunks = COUT / COC;
    const int tX = Wout / 32, tY = Hout / 16;
    const int ch = b % chunks; b /= chunks;
    const int tx = b % tX; b /= tX;
    const int ty = b % tY; const int n = b / tY;
    const int cobase = ch * COC;
    const int r = tid >> 4, c = tid & 15;
    const int gy0 = ty * 32 - 1, gx0 = tx * 64 - 1;

    v4f acc[16];
#pragma unroll
    for (int g = 0; g < 8; ++g) {
        v4f bv = *(const v4f*)&bias[cobase + 4 * g];
        acc[g] = bv; acc[8 + g] = bv;
    }

    const size_t plane = (size_t)Hin * Win;
    const float* ip0 = in + (size_t)n * CIN * plane;
    const float* wp0 = wp + cobase;

    for (int ci0 = 0; ci0 < CIN; ci0 += CB) {
        __syncthreads();
        for (int idx = tid; idx < CB * 2178; idx += 256) {
            int ci = idx / 2178, rem = idx - ci * 2178;
            int rr = rem / 66, cc = rem - rr * 66;
            int gy = gy0 + rr, gx = gx0 + cc;
            float v = 0.f;
            if (gy >= 0 && gy < Hin && gx >= 0 && gx < Win)
                v = ip0[(size_t)(ci0 + ci) * plane + (size_t)gy * Win + gx];
            smIn[idx] = v;
        }
        for (int idx = tid; idx < CB * 9 * COC; idx += 256) {
            int q2 = idx >> 5, co = idx & 31;
            smW[idx] = wp0[((size_t)ci0 * 9 + q2) * COUT + co];
        }
        __syncthreads();

#pragma unroll 1
        for (int ci = 0; ci < CB; ++ci) {
            float p[15];
            const float* sp = &smIn[ci * 2178 + 2 * r * 66 + 4 * c];
#pragma unroll
            for (int i = 0; i < 3; ++i)
#pragma unroll
                for (int j = 0; j < 5; ++j)
                    p[i * 5 + j] = sp[i * 66 + j];
            const float* wrow = &smW[ci * 288];
#pragma unroll
            for (int k = 0; k < 9; ++k) {
                const int ky = k / 3, kx = k % 3;
#pragma unroll
                for (int g = 0; g < 8; ++g) {
                    v4f wv = *(const v4f*)&wrow[k * 32 + 4 * g];
                    fma4(acc[g],     p[ky * 5 + kx],     wv);
                    fma4(acc[8 + g], p[ky * 5 + kx + 2], wv);
                }
            }
        }
    }

    const size_t outPlane = (size_t)Hout * Wout;
    const int oy = ty * 16 + r, ox = tx * 32 + 2 * c;
    float* op = out + ((size_t)n * COUT + cobase) * outPlane + (size_t)oy * Wout + ox;
#pragma unroll
    for (int g = 0; g < 8; ++g)
#pragma unroll
        for (int e = 0; e < 4; ++e) {
            float v0 = acc[g][e], v1 = acc[8 + g][e];
            if (RELU) { v0 = fmaxf(v0, 0.f); v1 = fmaxf(v1, 0.f); }
            *(float2*)&op[(size_t)(4 * g + e) * outPlane] = make_float2(v0, v1);
        }
}

// ===================== 1x1 conv stride S — 1 pos/thread, 32 co ==============
template<int CIN, int S, bool RELU>
__launch_bounds__(256, 4)
__global__ void conv1x1_k(const float* __restrict__ in, const float* __restrict__ w,
                          const float* __restrict__ bias, float* __restrict__ out,
                          int COUT, int Hin, int Win, int Hout, int Wout)
{
    constexpr int COC = 32;
    __shared__ float smW[CIN * COC];
    const int tid = threadIdx.x;
    int b = blockIdx.x;
    const int chunks = COUT / COC;
    const int spB = (Hout * Wout) / 256;
    const int ch = b % chunks; b /= chunks;
    const int sb = b % spB; const int n = b / spB;
    const int cobase = ch * COC;

    for (int idx = tid; idx < CIN * COC; idx += 256) {
        int ci = idx / COC, co = idx - ci * COC;
        smW[idx] = w[(size_t)(cobase + co) * CIN + ci];
    }
    __syncthreads();

    const int pos = sb * 256 + tid;
    const int oy = pos / Wout, ox = pos - oy * Wout;

    v4f acc[8];
#pragma unroll
    for (int g = 0; g < 8; ++g) acc[g] = *(const v4f*)&bias[cobase + 4 * g];

    const size_t inPlane = (size_t)Hin * Win;
    const float* ip = in + (size_t)n * CIN * inPlane + (size_t)(oy * S) * Win + (size_t)(ox * S);
#pragma unroll 1
    for (int ci = 0; ci < CIN; ++ci) {
        float v = ip[(size_t)ci * inPlane];
#pragma unroll
        for (int g = 0; g < 8; ++g)
            fma4(acc[g], v, *(const v4f*)&smW[ci * COC + 4 * g]);
    }
    const size_t outPlane = (size_t)Hout * Wout;
    float* op = out + ((size_t)n * COUT + cobase) * outPlane + pos;
#pragma unroll
    for (int g = 0; g < 8; ++g)
#pragma unroll
        for (int e = 0; e < 4; ++e) {
            float v = acc[g][e];
            if (RELU) v = fmaxf(v, 0.f);
            op[(size_t)(4 * g + e) * outPlane] = v;
        }
}

// ============================== quantize ===================================
__launch_bounds__(256)
__global__ void quantize_k(const float* __restrict__ h, const float* __restrict__ cb,
                           float* __restrict__ q)
{
    __shared__ float cn[512];
    __shared__ float cbl[128 * 64];
    const int tid = threadIdx.x;

    for (int i = tid; i < 512; i += 256) {
        float s = 0.f;
#pragma unroll
        for (int j = 0; j < 64; ++j) { float v = cb[i * 64 + j]; s = fmaf(v, v, s); }
        cn[i] = s;
    }

    const int t = blockIdx.x * 256 + tid;
    const int n = t >> 12, rem = t & 4095;
    const float* hp = h + (size_t)n * 64 * 4096 + rem;
    float e[64];
#pragma unroll
    for (int j = 0; j < 64; ++j) e[j] = hp[(size_t)j * 4096];

    float best = 3.4e38f; int bi = 0;
    for (int chn = 0; chn < 4; ++chn) {
        __syncthreads();
        const float4* src = reinterpret_cast<const float4*>(cb + chn * 128 * 64);
        float4* dst = reinterpret_cast<float4*>(cbl);
        for (int i = tid; i < 128 * 64 / 4; i += 256) dst[i] = src[i];
        __syncthreads();
        for (int c = 0; c < 128; ++c) {
            float dot = 0.f;
#pragma unroll
            for (int j = 0; j < 64; ++j) dot = fmaf(e[j], cbl[c * 64 + j], dot);
            float d = cn[chn * 128 + c] - 2.f * dot;
            if (d < best) { best = d; bi = chn * 128 + c; }
        }
    }

    const float* crow = cb + (size_t)bi * 64;
    float* qp = q + (size_t)n * 64 * 4096 + rem;
#pragma unroll
    for (int j = 0; j < 64; ++j) qp[(size_t)j * 4096] = crow[j];
}

extern "C" void kernel_launch(void* const* d_in, const int* in_sizes, int n_in,
                              void* d_out, int out_size, void* d_ws, size_t ws_size,
                              hipStream_t stream)
{
    const float* x    = (const float*)d_in[0];
    const float* e0w1 = (const float*)d_in[1];  const float* e0b1 = (const float*)d_in[2];
    const float* e0w2 = (const float*)d_in[3];  const float* e0b2 = (const float*)d_in[4];
    const float* e0wd = (const float*)d_in[5];  const float* e0bd = (const float*)d_in[6];
    const float* e1w1 = (const float*)d_in[7];  const float* e1b1 = (const float*)d_in[8];
    const float* e1w2 = (const float*)d_in[9];  const float* e1b2 = (const float*)d_in[10];
    const float* e1wd = (const float*)d_in[11]; const float* e1bd = (const float*)d_in[12];
    const float* e2w1 = (const float*)d_in[13]; const float* e2b1 = (const float*)d_in[14];
    const float* e2w2 = (const float*)d_in[15]; const float* e2b2 = (const float*)d_in[16];
    const float* e2wd = (const float*)d_in[17]; const float* e2bd = (const float*)d_in[18];
    const float* d0w  = (const float*)d_in[19]; const float* d0b  = (const float*)d_in[20];
    const float* d1w  = (const float*)d_in[21]; const float* d1b  = (const float*)d_in[22];
    const float* d2w  = (const float*)d_in[23]; const float* d2b  = (const float*)d_in[24];
    const float* cb   = (const float*)d_in[25];
    float* out = (float*)d_out;
    float* ws  = (float*)d_ws;

    // ---- packs in d_out slack (d_out only written by the final dec2) ----
    float* P_e0w1 = out + 0;            // fp32 pack, 1728
    _Float16* Bh_e0c2 = (_Float16*)(out + 77760);
    _Float16* Bl_e0c2 = (_Float16*)(out + 96192);
    _Float16* Bh_e1c2 = (_Float16*)(out + 114624);
    _Float16* Bl_e1c2 = (_Float16*)(out + 188352);
    _Float16* Bh_e2c1 = (_Float16*)(out + 262080);
    _Float16* Bl_e2c1 = (_Float16*)(out + 298944);
    _Float16* Bh_e2c2 = (_Float16*)(out + 335808);
    _Float16* Bl_e2c2 = (_Float16*)(out + 354240);
    _Float16* Bh_d0   = (_Float16*)(out + 372672);
    _Float16* Bl_d0   = (_Float16*)(out + 409536);
    _Float16* Bh_e1c1 = (_Float16*)(out + 446400);  // 73728 halves
    _Float16* Bl_e1c1 = (_Float16*)(out + 483264);

    // dec ConvT packs: in ws (read during dec1/dec2 while d_out is written);
    // placed in the dead-S1 zone, packed after S1's last reader.
    _Float16* BT1h = (_Float16*)(ws + 50331648);    // 131072 halves (65536 fl)
    _Float16* BT1l = (_Float16*)(ws + 50397184);
    _Float16* BT2h = (_Float16*)(ws + 50462720);    // 16384 halves (8192 fl)
    _Float16* BT2l = (_Float16*)(ws + 50470912);

    // ---- ws activation layout (floats), liveness-planned ----
    float* S0 = ws;                     // [0, 33.5M)  enc0 out
    float* T1 = ws + 33554432;          // enc0 conv1 out (full batch)
    float* T3 = ws + 33554432;          // enc1 conv1 out
    float* S1 = ws + 50331648;          // enc1 out
    float* S2 = ws;                     // enc2 out
    float* T5 = ws + 8388608;
    float* Q  = ws + 16777216;
    float* D0 = ws + 33554432;          // dec0 out
    float* D1 = ws;                     // dec1 out

    dim3 blk(256);
    auto rp = [&](const float* src, float* dst, int cout, int coutR, int cin, int flip, int dec) {
        int tot = cin * 9 * cout;
        repack_k<<<dim3((tot + 255) / 256), blk, 0, stream>>>(src, dst, cout, coutR, cin, flip, dec);
    };
    auto rpB = [&](const float* src, _Float16* bh, _Float16* bl, int cout, int cin, int dec) {
        int tot = 9 * cin * cout;
        repackB16_k<<<dim3((tot + 255) / 256), blk, 0, stream>>>(src, bh, bl, cout, cin, dec);
    };
    auto rpT = [&](const float* src, _Float16* bh, _Float16* bl, int coutR, int NG, int cin) {
        int tot = 16 * (cin >> 5) * NG * 512;
        repackBT_k<<<dim3((tot + 255) / 256), blk, 0, stream>>>(src, bh, bl, coutR, NG, cin);
    };

    rp(e0w1, P_e0w1, 64, 64, 3, 0, 0);
    rpB(e0w2, Bh_e0c2, Bl_e0c2, 64, 64, 0);
    rpB(e1w1, Bh_e1c1, Bl_e1c1, 128, 64, 0);
    rpB(e1w2, Bh_e1c2, Bl_e1c2, 128, 128, 0);
    rpB(e2w1, Bh_e2c1, Bl_e2c1, 64, 128, 0);
    rpB(e2w2, Bh_e2c2, Bl_e2c2, 64, 64, 0);
    rpB(d0w,  Bh_d0,   Bl_d0,   128, 64, 1);   // ConvT s1 == flipped conv

    // --- enc0 (3 -> 64, s2): 256 -> 128 ---
    conv1x1_k<3, 2, false><<<dim3(32 * 64 * 2), blk, 0, stream>>>(
        x, e0wd, e0bd, S0, 64, 256, 256, 128, 128);
    conv3s2_k<3, 3, true><<<dim3(32 * 8 * 4 * 2), blk, 0, stream>>>(
        x, P_e0w1, e0b1, T1, 64, 256, 256);
    mconv3s1_k<64, true, true><<<dim3(32 * 16 * 8 * 1), blk, 0, stream>>>(
        T1, Bh_e0c2, Bl_e0c2, e0b2, S0, S0, 64, 128, 128);

    // --- enc1 (64 -> 128, s2): 128 -> 64 ---
    conv1x1_k<64, 2, false><<<dim3(32 * 16 * 4), blk, 0, stream>>>(
        S0, e1wd, e1bd, S1, 128, 128, 128, 64, 64);
    mconv3s2_k<64, true><<<dim3(32 * 8 * 8 * 4), blk, 0, stream>>>(
        S0, Bh_e1c1, Bl_e1c1, e1b1, T3, 128, 128, 128);
    mconv3s1_k<128, true, true><<<dim3(32 * 8 * 4 * 2), blk, 0, stream>>>(
        T3, Bh_e1c2, Bl_e1c2, e1b2, S1, S1, 128, 64, 64);

    // --- enc2 (128 -> 64, s1) ---
    conv1x1_k<128, 1, false><<<dim3(32 * 16 * 2), blk, 0, stream>>>(
        S1, e2wd, e2bd, S2, 64, 64, 64, 64, 64);
    mconv3s1_k<128, true, false><<<dim3(32 * 8 * 4 * 1), blk, 0, stream>>>(
        S1, Bh_e2c1, Bl_e2c1, e2b1, T5, nullptr, 64, 64, 64);
    // S1 dead after the two reads above -> pack dec ConvT weights into its zone
    rpT(d1w, BT1h, BT1l, 64, 4, 128);
    rpT(d2w, BT2h, BT2l, 3, 1, 64);
    mconv3s1_k<64, true, true><<<dim3(32 * 8 * 4 * 1), blk, 0, stream>>>(
        T5, Bh_e2c2, Bl_e2c2, e2b2, S2, S2, 64, 64, 64);

    // --- quantize ---
    quantize_k<<<dim3(512), blk, 0, stream>>>(S2, cb, Q);

    // --- dec0: ConvT s1 (64 -> 128) as flipped conv, ReLU ---
    mconv3s1_k<64, true, false><<<dim3(32 * 8 * 4 * 2), blk, 0, stream>>>(
        Q, Bh_d0, Bl_d0, d0b, D0, nullptr, 128, 64, 64);

    // --- dec1: ConvT s2 (128 -> 64), ReLU: 64 -> 128 ---
    mdeconv2_k<128, 4, true><<<dim3(32 * 8 * 4), blk, 0, stream>>>(
        D0, BT1h, BT1l, d1b, D1, 64, 64, 64);

    // --- dec2: ConvT s2 (64 -> 3): 128 -> 256 ---
    mdeconv2_k<64, 1, false><<<dim3(32 * 16 * 8), blk, 0, stream>>>(
        D1, BT2h, BT2l, d2b, out, 3, 128, 128);
}